// Round 1
// 10249.857 us; speedup vs baseline: 1.5522x; 1.5522x over previous
//
#include <hip/hip_runtime.h>
#include <math.h>

#define HID  512
#define SEQL 256
#define BATCH 2048
#define NCLS 10
#define NB   8      // batch columns per workgroup

typedef _Float16 h2 __attribute__((ext_vector_type(2)));

__device__ __forceinline__ unsigned int pack2(float a, float b) {
    h2 p;
    p.x = (_Float16)a;
    p.y = (_Float16)b;
    return __builtin_bit_cast(unsigned int, p);
}

__device__ __forceinline__ float dot2f(unsigned int hu, unsigned int wu, float acc) {
    return __builtin_amdgcn_fdot2(__builtin_bit_cast(h2, hu),
                                  __builtin_bit_cast(h2, wu), acc, false);
}

// Transpose + f16-pack the 4 recurrent weight matrices [H][H] (w[j][k]) into
// wq[chunk=k/8][j][p=0..3] : uint4 per (k2=k/2, j) holding the 4 gates' f16
// k-pairs (w[j][2k2], w[j][2k2+1]).  One dwordx4 per lane covers 2 k's x 4 gates.
__global__ void pack_w(const float* __restrict__ w0, const float* __restrict__ w1,
                       const float* __restrict__ w2, const float* __restrict__ w3,
                       uint4* __restrict__ wq)
{
    __shared__ float tile[4][32][33];
    const int jb = blockIdx.x * 32;
    const int kb = blockIdx.y * 32;
    const int tx = threadIdx.x, ty = threadIdx.y;   // 32 x 8
    const float* ws[4] = {w0, w1, w2, w3};
    #pragma unroll
    for (int g = 0; g < 4; g++) {
        const float* w = ws[g];
        #pragma unroll
        for (int r = 0; r < 32; r += 8)
            tile[g][ty + r][tx] = w[(jb + ty + r) * HID + (kb + tx)];
    }
    __syncthreads();
    // 32 k's per tile -> 16 k-pairs; j = jb + tx (coalesced 16B stores)
    #pragma unroll
    for (int r = 0; r < 16; r += 8) {
        const int kk  = ty + r;            // 0..15
        const int k2g = kb / 2 + kk;       // global k-pair index
        uint4 v;
        v.x = pack2(tile[0][tx][2 * kk], tile[0][tx][2 * kk + 1]);
        v.y = pack2(tile[1][tx][2 * kk], tile[1][tx][2 * kk + 1]);
        v.z = pack2(tile[2][tx][2 * kk], tile[2][tx][2 * kk + 1]);
        v.w = pack2(tile[3][tx][2 * kk], tile[3][tx][2 * kk + 1]);
        wq[((k2g >> 2) * HID + (jb + tx)) * 4 + (k2g & 3)] = v;
    }
}

// Persistent LSTM: each workgroup owns NB=8 batch columns for all 256 steps.
// Thread j owns hidden row j: 4 gate f32 accumulators x 8 columns, cell state
// in registers; h broadcast through LDS as f16 (double-buffered, 1 barrier/step).
// Inner product uses v_dot2_f32_f16: 2 MACs/lane/instr, f32 accumulate.
__global__ __launch_bounds__(512, 2) void lstm_persist(
    const float* __restrict__ x,                                   // [B][SEQ]
    const float* __restrict__ wgx, const float* __restrict__ wix,
    const float* __restrict__ wfx, const float* __restrict__ wox,  // [H]
    const float* __restrict__ bg,  const float* __restrict__ bi,
    const float* __restrict__ bf_, const float* __restrict__ bo,   // [H]
    const uint4* __restrict__ wq,                                  // packed f16 weights
    const float* __restrict__ wph, const float* __restrict__ bp,   // [C][H], [C]
    const float* __restrict__ h_init, const float* __restrict__ c_init, // [H]
    float* __restrict__ out)                                       // [B][C]
{
    __shared__ __align__(16) _Float16 h16[2][NB][HID];  // 16 KB, [buf][col][k]
    __shared__ float x_s[NB * SEQL];                    // 8 KB

    const int j  = threadIdx.x;          // 0..511 = hidden row
    const int b0 = blockIdx.x * NB;      // first batch column of this WG

    // Preload this WG's x slice (coalesced along t).
    for (int i = j; i < NB * SEQL; i += 512)
        x_s[i] = x[(b0 + i / SEQL) * SEQL + (i % SEQL)];

    const float wxg = wgx[j], wxi = wix[j], wxf = wfx[j], wxo = wox[j];
    const float bgj = bg[j],  bij = bi[j],  bfj = bf_[j], boj = bo[j];

    float c_reg[NB];
    {
        const float c0 = c_init[j];
        const _Float16 h0 = (_Float16)h_init[j];
        #pragma unroll
        for (int c = 0; c < NB; c++) {
            c_reg[c] = c0;
            h16[0][c][j] = h0;
        }
    }
    __syncthreads();

    int cur = 0;
    for (int t = 0; t < SEQL; t++) {
        // Weight pointer for this step; chunk layout: stride HID*4 uint4 per 8 k's.
        const uint4* wp = wq + j * 4;
        uint4 wv0 = wp[0], wv1 = wp[1], wv2 = wp[2], wv3 = wp[3];

        float ag[NB], ai[NB], af[NB], ao[NB];
        #pragma unroll
        for (int c = 0; c < NB; c++) {
            const float xv = x_s[c * SEQL + t];
            ag[c] = fmaf(wxg, xv, bgj);
            ai[c] = fmaf(wxi, xv, bij);
            af[c] = fmaf(wxf, xv, bfj);
            ao[c] = fmaf(wxo, xv, boj);
        }

        // K-loop: 8 k's (4 k-pairs) per iteration.
        //   weights: 4 x dwordx4, prefetched one chunk ahead (over-read of the
        //            last prefetch stays inside the 4 MiB workspace).
        //   h:       1 x ds_read_b128 broadcast per column (8 k's of f16).
        #pragma unroll 1
        for (int k0 = 0; k0 < HID; k0 += 8) {
            wp += HID * 4;
            const uint4 nv0 = wp[0], nv1 = wp[1], nv2 = wp[2], nv3 = wp[3];

            uint4 hv[NB];
            #pragma unroll
            for (int c = 0; c < NB; c++)
                hv[c] = *reinterpret_cast<const uint4*>(&h16[cur][c][k0]);

            #pragma unroll
            for (int c = 0; c < NB; c++) {
                const uint4 hvc = hv[c];
                ag[c] = dot2f(hvc.x, wv0.x, ag[c]);
                ai[c] = dot2f(hvc.x, wv0.y, ai[c]);
                af[c] = dot2f(hvc.x, wv0.z, af[c]);
                ao[c] = dot2f(hvc.x, wv0.w, ao[c]);
                ag[c] = dot2f(hvc.y, wv1.x, ag[c]);
                ai[c] = dot2f(hvc.y, wv1.y, ai[c]);
                af[c] = dot2f(hvc.y, wv1.z, af[c]);
                ao[c] = dot2f(hvc.y, wv1.w, ao[c]);
                ag[c] = dot2f(hvc.z, wv2.x, ag[c]);
                ai[c] = dot2f(hvc.z, wv2.y, ai[c]);
                af[c] = dot2f(hvc.z, wv2.z, af[c]);
                ao[c] = dot2f(hvc.z, wv2.w, ao[c]);
                ag[c] = dot2f(hvc.w, wv3.x, ag[c]);
                ai[c] = dot2f(hvc.w, wv3.y, ai[c]);
                af[c] = dot2f(hvc.w, wv3.z, af[c]);
                ao[c] = dot2f(hvc.w, wv3.w, ao[c]);
            }
            wv0 = nv0; wv1 = nv1; wv2 = nv2; wv3 = nv3;
        }

        const int nxt = cur ^ 1;
        #pragma unroll
        for (int c = 0; c < NB; c++) {
            const float g  = tanhf(ag[c]);
            const float ii = 1.f / (1.f + expf(-ai[c]));
            const float ff = 1.f / (1.f + expf(-af[c]));
            const float oo = 1.f / (1.f + expf(-ao[c]));
            const float cc = fmaf(g, ii, c_reg[c] * ff);
            c_reg[c] = cc;
            h16[nxt][c][j] = (_Float16)(tanhf(cc) * oo);
        }
        __syncthreads();   // writes to nxt done; safe to read next step
        cur = nxt;
    }

    // Epilogue: out[b][cls] = bp[cls] + sum_k wph[cls][k] * h[k][b]
    if (j < NB * NCLS) {
        const int col = j / NCLS, cls = j % NCLS;
        float s = bp[cls];
        for (int k = 0; k < HID; k++)
            s = fmaf(wph[cls * HID + k], (float)h16[cur][col][k], s);
        out[(b0 + col) * NCLS + cls] = s;
    }
}

extern "C" void kernel_launch(void* const* d_in, const int* in_sizes, int n_in,
                              void* d_out, int out_size, void* d_ws, size_t ws_size,
                              hipStream_t stream)
{
    const float* x   = (const float*)d_in[0];
    const float* wgx = (const float*)d_in[1];
    const float* wix = (const float*)d_in[2];
    const float* wfx = (const float*)d_in[3];
    const float* wox = (const float*)d_in[4];
    const float* wgh = (const float*)d_in[5];
    const float* wih = (const float*)d_in[6];
    const float* wfh = (const float*)d_in[7];
    const float* woh = (const float*)d_in[8];
    const float* bg  = (const float*)d_in[9];
    const float* bi  = (const float*)d_in[10];
    const float* bf  = (const float*)d_in[11];
    const float* bo  = (const float*)d_in[12];
    const float* wph = (const float*)d_in[13];
    const float* bp  = (const float*)d_in[14];
    const float* h0  = (const float*)d_in[15];
    const float* c0  = (const float*)d_in[16];
    float* out = (float*)d_out;
    uint4* wq  = (uint4*)d_ws;   // 2 MiB packed f16 weights (+32 KiB prefetch slack)

    pack_w<<<dim3(16, 16), dim3(32, 8), 0, stream>>>(wgh, wih, wfh, woh, wq);
    lstm_persist<<<dim3(BATCH / NB), dim3(512), 0, stream>>>(
        x, wgx, wix, wfx, wox, bg, bi, bf, bo, wq, wph, bp, h0, c0, out);
}